// Round 13
// baseline (194.883 us; speedup 1.0000x reference)
//
#include <hip/hip_runtime.h>
#include <hip/hip_bf16.h>
#include <cstdint>

#define NN    50000
#define NE    1600000
#define DIN   256
#define DOUT  64
#define CAPS  96      // col stride (u16): slot 0 = count, slots 1..95 = dsts
#define CAPD  95      // max stored out-degree (Poisson(32): P(>=95) ~ 1e-18)

#define BKT   196     // coarse buckets: src>>8 (256 nodes each), 49999>>8 = 195
#define BCAP  10240   // edges per coarse bucket capacity (mean 8192, sigma 90)
#define EPB   4096    // edges per binning block
#define EPT   16      // EPB / 256
#define NBIN  391     // ceil(NE / EPB)
#define MTB   32      // rows per gemm block (16KB A-tile, round-12 verified)
#define NGEMM 1563    // ceil(NN / MTB)
#define NCSR  800     // csr role blocks (196 buckets x 4 parts, XCD-grouped)
#define GSPL  650     // gemm blocks in fused1 (balanced against bin ~18us)

typedef __attribute__((ext_vector_type(8))) short frag8;   // 8 bf16 (4 VGPRs)
typedef __attribute__((ext_vector_type(4))) float fragc;   // 4 fp32 acc

union PK { __hip_bfloat162 b2; uint32_t u; };
union CH { frag8 v; uint32_t u[4]; };

__device__ __forceinline__ float leaky01(float x) { return x >= 0.f ? x : 0.01f * x; }

__device__ __forceinline__ uint32_t pk2(float lo, float hi) {
  PK p; p.b2 = __float22bfloat162_rn(make_float2(lo, hi)); return p.u;  // (hi<<16)|lo
}

__device__ __forceinline__ int   bcast_i(int v, int lane) {
  return __builtin_amdgcn_readlane(v, lane);
}

// bf16 pair unpack: u = (Lbits<<16) | Hbits
__device__ __forceinline__ float bfH(uint32_t u) { return __uint_as_float(u << 16); }
__device__ __forceinline__ float bfL(uint32_t u) { return __uint_as_float(u & 0xffff0000u); }

// -------------------------------------------------------------------------
// prep: zero bucket cursors + build Wt = bf16 transposed weights [m][n][k]
// -------------------------------------------------------------------------
__global__ __launch_bounds__(256) void prep_kernel(
    const float* __restrict__ Wh, const float* __restrict__ Wl,
    __hip_bfloat16* __restrict__ Wt, int* __restrict__ cursor)
{
  if (blockIdx.x == 0 && threadIdx.x < BKT) cursor[threadIdx.x] = 0;
  int g = blockIdx.x * 256 + threadIdx.x;
  if (g < 2 * DOUT * DIN) {
    int m = g >> 14, rem = g & 16383;
    int n = rem >> 8, k = rem & 255;
    float v = (m ? Wl : Wh)[k * DOUT + n];
    Wt[g] = __float2bfloat16(v);
  }
}

// -------------------------------------------------------------------------
// gemm role (round-12 verified, MTB=32): B frags prefetched once per wave;
// coalesced A-staging with XOR involution B ^= ((B>>8)&7)<<4 on both sides;
// pure LDS+MFMA inner loop; epilogue writes packed HL + per-node scalars.
// -------------------------------------------------------------------------
__device__ __forceinline__ void gemm_role(
    int gid, const float* __restrict__ inp, const __hip_bfloat16* __restrict__ Wt,
    const float* __restrict__ ah, const float* __restrict__ al,
    uint32_t* __restrict__ HL, float2* __restrict__ ss, char* smem, int t)
{
  const int n0 = gid * MTB;
  const int lane = t & 63;
  const int w = t >> 6;                    // wave id: owns cols w*16..w*16+15
  const int quad = lane >> 4, nn = lane & 15;

  const frag8* Wt8 = (const frag8*)Wt;
  const int bbase = ((w * 16 + nn) << 5) + quad;
  frag8 bH[8], bL[8];
#pragma unroll
  for (int q = 0; q < 8; q++) {
    bH[q] = Wt8[bbase + (q << 2)];
    bL[q] = Wt8[2048 + bbase + (q << 2)];
  }

  // Stage A tile (32 rows x 256 k) coalesced; swizzle B ^= ((B>>8)&7)<<4.
  const float4* inp4 = (const float4*)inp;
  const int l5 = t & 31;
  const int rw = t >> 5;                   // row-within-group 0..7
  {
    const int q8 = l5 >> 2, qd = l5 & 3;
#pragma unroll
    for (int i = 0; i < 4; i++) {
      int row = i * 8 + rw;
      int node = n0 + row;
      float4 a0 = make_float4(0.f, 0.f, 0.f, 0.f), a1 = a0;
      if (node < NN) {
        a0 = inp4[(size_t)node * 64 + l5 * 2];
        a1 = inp4[(size_t)node * 64 + l5 * 2 + 1];
      }
      int c = ((row >> 4) << 9) | (q8 << 6) | (qd << 4) | (row & 15);
      int B = c << 4;
      B ^= ((B >> 8) & 7) << 4;
      CH ch;
      ch.u[0] = pk2(a0.x, a0.y);
      ch.u[1] = pk2(a0.z, a0.w);
      ch.u[2] = pk2(a1.x, a1.y);
      ch.u[3] = pk2(a1.z, a1.w);
      *(frag8*)(smem + B) = ch.v;
    }
  }
  __syncthreads();

  fragc accH[2], accL[2];
#pragma unroll
  for (int m = 0; m < 2; m++) {
    accH[m] = (fragc){0.f, 0.f, 0.f, 0.f};
    accL[m] = (fragc){0.f, 0.f, 0.f, 0.f};
  }

  // Pure LDS+MFMA inner loop: 16 swizzled ds_read_b128 + 32 MFMA per wave.
#pragma unroll
  for (int q = 0; q < 8; q++) {
#pragma unroll
    for (int mt = 0; mt < 2; mt++) {
      int R = (mt << 13) + (q << 10) + (lane << 4);
      R ^= ((R >> 8) & 7) << 4;
      frag8 af = *(const frag8*)(smem + R);  // A[m=nn][k=q*32+quad*8+j]
      accH[mt] = __builtin_amdgcn_mfma_f32_16x16x32_bf16(af, bH[q], accH[mt], 0, 0, 0);
      accL[mt] = __builtin_amdgcn_mfma_f32_16x16x32_bf16(af, bL[q], accL[mt], 0, 0, 0);
    }
  }
  __syncthreads();           // A-tile dead; reuse smem for cross-wave reduce

  // Epilogue: C/D mapping col=lane&15 (n), row=quad*4+reg (m89-verified).
  float* sred = (float*)smem;
  const float ahv = ah[w * 16 + nn];
  const float alv = al[w * 16 + nn];
#pragma unroll
  for (int mt = 0; mt < 2; mt++) {
#pragma unroll
    for (int r = 0; r < 4; r++) {
      int rowb = (mt << 4) + (quad << 2) + r;
      int node = n0 + rowb;
      float hH = leaky01(accH[mt][r]);
      float hL = leaky01(accL[mt][r]);
      if (node < NN) HL[(size_t)node * DOUT + w * 16 + nn] = pk2(hH, hL);
      float pH = hH * ahv, pL = hL * alv;
#pragma unroll
      for (int off = 1; off < 16; off <<= 1) {   // reduce over the 16-col slice
        pH += __shfl_xor(pH, off);
        pL += __shfl_xor(pL, off);
      }
      if (nn == 0) {
        sred[rowb * 8 + w]     = pH;
        sred[rowb * 8 + 4 + w] = pL;
      }
    }
  }
  __syncthreads();
  if (t < 32) {
    int node = n0 + t;
    if (node < NN) {
      float sH = sred[t * 8 + 0] + sred[t * 8 + 1] + sred[t * 8 + 2] + sred[t * 8 + 3];
      float sL = sred[t * 8 + 4] + sred[t * 8 + 5] + sred[t * 8 + 6] + sred[t * 8 + 7];
      ss[node] = make_float2(sH, sL);
    }
  }
}

// -------------------------------------------------------------------------
// fused1: bin(391) || gemm[0, GSPL). Binning co-runs with gemm (round-10/11
// lesson: bin must never be serial). LDS counting-sort into 196 buckets.
// -------------------------------------------------------------------------
__global__ __launch_bounds__(256) void fused1_kernel(
    const float* __restrict__ inp, const __hip_bfloat16* __restrict__ Wt,
    const float* __restrict__ ah, const float* __restrict__ al,
    const int* __restrict__ edge, int* __restrict__ cursor,
    uint32_t* __restrict__ binned, uint32_t* __restrict__ HL,
    float2* __restrict__ ss)
{
  __shared__ __align__(16) char smem[20480];   // overlay: binning stage / A frags

  const int idx = blockIdx.x;
  const int t = threadIdx.x;

  if (idx < NBIN) {
    // ---------------- binning role ----------------
    uint32_t* stage  = (uint32_t*)smem;                 // 16384 B
    int*      hist   = (int*)(smem + 16384);            // 1024 B (256, padded)
    int*      cur    = (int*)(smem + 17408);            // 784 B
    int*      base_g = (int*)(smem + 18192);            // 784 B
    int*      scan_s = (int*)(smem + 18976);            // 788 B (ends 19764)

    const int e0 = idx * EPB;
    uint32_t v[EPT];
#pragma unroll
    for (int i = 0; i < EPT; i++) {
      int e = e0 + i * 256 + t;
      if (e < NE) {
        uint32_t s = (uint32_t)edge[e];
        uint32_t d = (uint32_t)edge[NE + e];
        v[i] = (s << 16) | d;            // bin = v >> 24 = src >> 8
      } else {
        v[i] = 0xFFFFFFFFu;              // bin 255 -> skipped
      }
    }
    hist[t] = 0;
    for (int b = t; b < BKT; b += 256) cur[b] = 0;
    __syncthreads();
#pragma unroll
    for (int i = 0; i < EPT; i++) {
      int b = v[i] >> 24;
      if (b < BKT) atomicAdd(&hist[b], 1);
    }
    __syncthreads();
    if (t < 64) {
      // wave 0: exclusive scan of hist[0..255] via shuffle, 4 segments
      int carry = 0;
#pragma unroll
      for (int seg = 0; seg < 4; seg++) {
        int i = seg * 64 + t;
        int h = hist[i];
        int s = h;                       // inclusive scan within segment
#pragma unroll
        for (int off = 1; off < 64; off <<= 1) {
          int o = __shfl_up(s, off);
          if (t >= off) s += o;
        }
        int excl = carry + s - h;
        if (i <= BKT) scan_s[i] = excl;  // scan_s[BKT] = grand total
        carry += bcast_i(s, 63);
      }
    }
    __syncthreads();
    for (int b = t; b < BKT; b += 256) {
      int h = hist[b];
      base_g[b] = h ? atomicAdd(&cursor[b], h) : 0;
    }
    __syncthreads();
#pragma unroll
    for (int i = 0; i < EPT; i++) {
      int b = v[i] >> 24;
      if (b < BKT) {
        int pos = atomicAdd(&cur[b], 1);
        stage[scan_s[b] + pos] = v[i];
      }
    }
    __syncthreads();
    const int total = scan_s[BKT];
    for (int i = t; i < total; i += 256) {
      uint32_t sv = stage[i];
      int bb = sv >> 24;                 // bucket known from value: no search
      int ofs = base_g[bb] + (i - scan_s[bb]);
      if (ofs < BCAP) binned[(size_t)bb * BCAP + ofs] = sv;
    }
    return;
  }

  gemm_role(idx - NBIN, inp, Wt, ah, al, HL, ss, smem, t);
}

// -------------------------------------------------------------------------
// fused2: csr(800) || gemm[GSPL, NGEMM). csr depends on fused1's bin output
// (cross-dispatch, safe); gemm half is independent — csr's ~13us hides under
// it instead of serializing. Wt NOT overlaid on col (race would result).
// csr XCD-grouping intact (csr blocks at idx 0..799; bucket parts differ by
// multiples of 8 -> same blockIdx%8 -> same XCD).
// -------------------------------------------------------------------------
__global__ __launch_bounds__(256) void fused2_kernel(
    const float* __restrict__ inp, const __hip_bfloat16* __restrict__ Wt,
    const float* __restrict__ ah, const float* __restrict__ al,
    const uint32_t* __restrict__ binned, const int* __restrict__ cursor,
    unsigned short* __restrict__ col, uint32_t* __restrict__ HL,
    float2* __restrict__ ss)
{
  __shared__ __align__(16) char smem[16640];   // overlay: csr lists / A frags

  const int idx = blockIdx.x;
  const int t = threadIdx.x;

  if (idx < NCSR) {
    // ---------------- csr role ----------------
    unsigned short (*lst)[CAPS] = (unsigned short (*)[CAPS])smem;  // 12288 B
    int* cnt = (int*)(smem + 12288);                               // 256 B
    const int b    = ((idx >> 5) << 3) + (idx & 7);   // bucket
    const int part = (idx >> 3) & 3;                  // 64-node slice
    if (b >= BKT) return;
    if (t < 64) cnt[t] = 0;
    __syncthreads();
    int n = cursor[b]; if (n > BCAP) n = BCAP;
    const uint32_t* eb = binned + (size_t)b * BCAP;
    for (int i = t; i < n; i += 256) {
      uint32_t v = eb[i];
      int src = v >> 16, dst = v & 0xffff;
      int loc = src & 255;
      if ((loc >> 6) == part) {
        int pos = atomicAdd(&cnt[loc & 63], 1);
        if (pos < CAPD) lst[loc & 63][1 + pos] = (unsigned short)dst;
      }
    }
    __syncthreads();
    if (t < 64) {
      int c = cnt[t]; if (c > CAPD) c = CAPD;
      lst[t][0] = (unsigned short)c;
    }
    __syncthreads();
    // stream out 64 rows x 96 u16 = 12288 B = 768 int4, fully coalesced
    const int base_node = (b << 8) + (part << 6);
    int4* dst4 = (int4*)(col + (size_t)base_node * CAPS);
    const int4* src4 = (const int4*)&lst[0][0];
    for (int i = t; i < 64 * CAPS / 8; i += 256) {
      int node = base_node + i / (CAPS / 8);
      if (node < NN) dst4[i] = src4[i];
    }
    return;
  }

  gemm_role(GSPL + idx - NCSR, inp, Wt, ah, al, HL, ss, smem, t);
}

// -------------------------------------------------------------------------
// agg (round-10/12 proven form, ~52 us): one wave per node; two edges per
// wave-instruction (lanes 0-31 even edge, 32-63 odd; dwordx2 covers the 256B
// HL row across a half-wave); ds_bpermute broadcasts; 4-pair batches; u16
// neighbor lists. Beyond-L2-BW bound (rounds 6/7/9 exhausted the levers).
// -------------------------------------------------------------------------
__global__ __launch_bounds__(256) void agg_kernel(
    const uint32_t* __restrict__ HL, const float2* __restrict__ ss,
    const unsigned short* __restrict__ col, float* __restrict__ out)
{
  int wave = (blockIdx.x * blockDim.x + threadIdx.x) >> 6;
  int lane = threadIdx.x & 63;
  if (wave >= NN) return;
  const int n = wave;
  const unsigned short* cl = col + (size_t)n * CAPS;
  int d = cl[0]; if (d > CAPD) d = CAPD;

  const float2 sn = ss[n];
  const uint2* HL2 = (const uint2*)HL;

  const int vodd4 = (lane & 32) >> 3;    // bperm byte-idx: +4 selects odd edge
  const int lo31  = lane & 31;           // uint2 slot within row

  float accH0 = 0.f, accH1 = 0.f, accL0 = 0.f, accL1 = 0.f;
  float rsH = 0.f, rsL = 0.f;

  for (int base = 0; base < d; base += 64) {
    int m = d - base; if (m > 64) m = 64;
    int   dst_l = 0;
    float eh_l = 0.f, el_l = 0.f;
    if (lane < m) {
      dst_l = cl[1 + base + lane];
      float2 sd = ss[dst_l];
      float xh = sn.x - sd.x;
      xh = (xh >= 0.f) ? xh : 0.2f * xh;
      eh_l = __expf(-xh);
      float xl = sn.y + sd.y;
      xl = (xl >= 0.f) ? xl : 0.2f * xl;
      el_l = __expf(-xl);
    }
    const int ehb = __float_as_int(eh_l);
    const int elb = __float_as_int(el_l);
    const int pj = (m + 1) >> 1;         // pairs in this chunk (<= 32)
    for (int jj = 0; jj < pj; jj += 4) { // 4 pairs = 8 edges per batch
      int vdd[4]; float veh[4], vel[4]; uint2 u[4];
#pragma unroll
      for (int x = 0; x < 4; x++) {
        int ib = vodd4 + ((jj + x) << 3);          // max 4+31*8=252 < 256
        vdd[x] = __builtin_amdgcn_ds_bpermute(ib, dst_l);
        veh[x] = __int_as_float(__builtin_amdgcn_ds_bpermute(ib, ehb));
        vel[x] = __int_as_float(__builtin_amdgcn_ds_bpermute(ib, elb));
      }
#pragma unroll
      for (int x = 0; x < 4; x++)
        u[x] = HL2[(((uint32_t)vdd[x]) << 5) + lo31];
#pragma unroll
      for (int x = 0; x < 4; x++) {
        accH0 += veh[x] * bfH(u[x].x);
        accL0 += vel[x] * bfL(u[x].x);
        accH1 += veh[x] * bfH(u[x].y);
        accL1 += vel[x] * bfL(u[x].y);
      }
    }
    // chunk row-sums: one butterfly over the wave (invalid lanes hold 0)
    float rh = eh_l, rl = el_l;
#pragma unroll
    for (int off = 1; off < 64; off <<= 1) {
      rh += __shfl_xor(rh, off);
      rl += __shfl_xor(rl, off);
    }
    rsH += rh; rsL += rl;
  }

  // combine even-edge (lanes 0-31) and odd-edge (lanes 32-63) partials:
  // lanes l and l+32 hold the same dim pair (2l, 2l+1).
  accH0 += __shfl_xor(accH0, 32);
  accH1 += __shfl_xor(accH1, 32);
  accL0 += __shfl_xor(accL0, 32);
  accL1 += __shfl_xor(accL1, 32);

  // lanes 0-31 write the H half (dims 2l,2l+1), lanes 32-63 the L half.
  float r  = (lane < 32) ? rsH : rsL;
  float a0 = (lane < 32) ? accH0 : accL0;
  float a1 = (lane < 32) ? accH1 : accL1;
  float inv = 1.f / (r + 1e-16f);
  float o0 = leaky01(a0 * inv);
  float o1 = leaky01(a1 * inv);
  float2* op = (float2*)(out + (size_t)n * 128 + ((lane & 32) << 1) + (lo31 << 1));
  *op = make_float2(o0, o1);
}

// -------------------------------------------------------------------------
extern "C" void kernel_launch(void* const* d_in, const int* in_sizes, int n_in,
                              void* d_out, int out_size, void* d_ws, size_t ws_size,
                              hipStream_t stream) {
  const float* inp  = (const float*)d_in[0];
  const int*   edge = (const int*)d_in[1];
  const float* Wh   = (const float*)d_in[2];
  const float* Wl   = (const float*)d_in[3];
  const float* ah   = (const float*)d_in[4];
  const float* al   = (const float*)d_in[5];
  float* out = (float*)d_out;

  char* ws = (char*)d_ws;
  uint32_t* HL     = (uint32_t*)(ws + 0);          // 12,800,000 B
  float2*   ss     = (float2*)  (ws + 12800000);   //    400,000 B
  unsigned short* col = (unsigned short*)(ws + 13200000);  // 9,600,000 B (u16)
  __hip_bfloat16* Wt  = (__hip_bfloat16*)(ws + 24000000);  // 65,536 B — NOT
             // overlaid on col: fused2 reads Wt while its csr role writes col
  uint32_t* binned = (uint32_t*)(ws + 32400000);   //  8,028,160 B
  int*      cursor = (int*)     (ws + 40428160);   //        784 B

  prep_kernel<<<128, 256, 0, stream>>>(Wh, Wl, Wt, cursor);
  fused1_kernel<<<NBIN + GSPL, 256, 0, stream>>>(inp, Wt, ah, al, edge,
                                                 cursor, binned, HL, ss);
  fused2_kernel<<<NCSR + (NGEMM - GSPL), 256, 0, stream>>>(inp, Wt, ah, al,
                                                 binned, cursor, col, HL, ss);
  agg_kernel<<<NN / 4, 256, 0, stream>>>(HL, ss, col, out);
}

// Round 14
// 190.245 us; speedup vs baseline: 1.0244x; 1.0244x over previous
//
#include <hip/hip_runtime.h>
#include <hip/hip_bf16.h>
#include <cstdint>

#define NN    50000
#define NE    1600000
#define DIN   256
#define DOUT  64
#define CAPS  96      // col stride (u16): slot 0 = count, slots 1..95 = dsts
#define CAPD  95      // max stored out-degree (Poisson(32): P(>=95) ~ 1e-18)

#define BKT   196     // coarse buckets: src>>8 (256 nodes each), 49999>>8 = 195
#define BCAP  10240   // edges per coarse bucket capacity (mean 8192, sigma 90)
#define EPB   4096    // edges per binning block
#define EPT   16      // EPB / 256
#define NBIN  391     // ceil(NE / EPB)
#define MTB   32      // rows per gemm block (halved: 16KB A-tile -> 2x occupancy)
#define NGEMM 1563    // ceil(NN / MTB)

typedef __attribute__((ext_vector_type(8))) short frag8;   // 8 bf16 (4 VGPRs)
typedef __attribute__((ext_vector_type(4))) float fragc;   // 4 fp32 acc

union PK { __hip_bfloat162 b2; uint32_t u; };
union CH { frag8 v; uint32_t u[4]; };

__device__ __forceinline__ float leaky01(float x) { return x >= 0.f ? x : 0.01f * x; }

__device__ __forceinline__ uint32_t pk2(float lo, float hi) {
  PK p; p.b2 = __float22bfloat162_rn(make_float2(lo, hi)); return p.u;  // (hi<<16)|lo
}

__device__ __forceinline__ int   bcast_i(int v, int lane) {
  return __builtin_amdgcn_readlane(v, lane);
}

// bf16 pair unpack: u = (Lbits<<16) | Hbits
__device__ __forceinline__ float bfH(uint32_t u) { return __uint_as_float(u << 16); }
__device__ __forceinline__ float bfL(uint32_t u) { return __uint_as_float(u & 0xffff0000u); }

// -------------------------------------------------------------------------
// prep: zero bucket cursors + build Wt = bf16 transposed weights [m][n][k]
// -------------------------------------------------------------------------
__global__ __launch_bounds__(256) void prep_kernel(
    const float* __restrict__ Wh, const float* __restrict__ Wl,
    __hip_bfloat16* __restrict__ Wt, int* __restrict__ cursor)
{
  if (blockIdx.x == 0 && threadIdx.x < BKT) cursor[threadIdx.x] = 0;
  int g = blockIdx.x * 256 + threadIdx.x;
  if (g < 2 * DOUT * DIN) {
    int m = g >> 14, rem = g & 16383;
    int n = rem >> 8, k = rem & 255;
    float v = (m ? Wl : Wh)[k * DOUT + n];
    Wt[g] = __float2bfloat16(v);
  }
}

// -------------------------------------------------------------------------
// Fused kernel (round-12 best, 192.3us total: binning co-runs with gemm in
// ONE dispatch — rounds 11/13 proved every alternative partition regresses):
//  blocks [0, NBIN): binning role — LDS counting-sort into 196 coarse buckets.
//  blocks [NBIN, NBIN+NGEMM): MFMA gemm role, MTB=32 rows (16KB A-tile +
//    20.5KB static smem raises LDS occupancy cap; gemm role is latency-bound
//    at MfmaUtil ~2%, resident-wave count is the lever). B frags prefetched
//    once; coalesced A-staging with XOR involution B ^= ((B>>8)&7)<<4.
// -------------------------------------------------------------------------
__global__ __launch_bounds__(256) void fused_kernel(
    const float* __restrict__ inp, const __hip_bfloat16* __restrict__ Wt,
    const float* __restrict__ ah, const float* __restrict__ al,
    const int* __restrict__ edge, int* __restrict__ cursor,
    uint32_t* __restrict__ binned, uint32_t* __restrict__ HL,
    float2* __restrict__ ss)
{
  __shared__ __align__(16) char smem[20480];   // overlay: binning stage / A frags

  const int idx = blockIdx.x;
  const int t = threadIdx.x;

  if (idx < NBIN) {
    // ---------------- binning role ----------------
    uint32_t* stage  = (uint32_t*)smem;                 // 16384 B
    int*      hist   = (int*)(smem + 16384);            // 1024 B (256, padded)
    int*      cur    = (int*)(smem + 17408);            // 784 B
    int*      base_g = (int*)(smem + 18192);            // 784 B
    int*      scan_s = (int*)(smem + 18976);            // 788 B (ends 19764)

    const int e0 = idx * EPB;
    uint32_t v[EPT];
#pragma unroll
    for (int i = 0; i < EPT; i++) {
      int e = e0 + i * 256 + t;
      if (e < NE) {
        uint32_t s = (uint32_t)edge[e];
        uint32_t d = (uint32_t)edge[NE + e];
        v[i] = (s << 16) | d;            // bin = v >> 24 = src >> 8
      } else {
        v[i] = 0xFFFFFFFFu;              // bin 255 -> skipped
      }
    }
    if (t < 256) hist[t] = 0;
    for (int b = t; b < BKT; b += 256) cur[b] = 0;
    __syncthreads();
#pragma unroll
    for (int i = 0; i < EPT; i++) {
      int b = v[i] >> 24;
      if (b < BKT) atomicAdd(&hist[b], 1);
    }
    __syncthreads();
    if (t < 64) {
      // wave 0: exclusive scan of hist[0..255] via shuffle, 4 segments
      int carry = 0;
#pragma unroll
      for (int seg = 0; seg < 4; seg++) {
        int i = seg * 64 + t;
        int h = hist[i];
        int s = h;                       // inclusive scan within segment
#pragma unroll
        for (int off = 1; off < 64; off <<= 1) {
          int o = __shfl_up(s, off);
          if (t >= off) s += o;
        }
        int excl = carry + s - h;
        if (i <= BKT) scan_s[i] = excl;  // scan_s[BKT] = grand total
        carry += bcast_i(s, 63);
      }
    }
    __syncthreads();
    for (int b = t; b < BKT; b += 256) {
      int h = hist[b];
      base_g[b] = h ? atomicAdd(&cursor[b], h) : 0;
    }
    __syncthreads();
#pragma unroll
    for (int i = 0; i < EPT; i++) {
      int b = v[i] >> 24;
      if (b < BKT) {
        int pos = atomicAdd(&cur[b], 1);
        stage[scan_s[b] + pos] = v[i];
      }
    }
    __syncthreads();
    const int total = scan_s[BKT];
    for (int i = t; i < total; i += 256) {
      uint32_t sv = stage[i];
      int bb = sv >> 24;                 // bucket known from value: no search
      int ofs = base_g[bb] + (i - scan_s[bb]);
      if (ofs < BCAP) binned[(size_t)bb * BCAP + ofs] = sv;
    }
    return;
  }

  // ---------------- MFMA gemm role (MTB=32) ----------------
  const int gid = idx - NBIN;              // 0 .. NGEMM-1
  const int n0 = gid * MTB;
  const int lane = t & 63;
  const int w = t >> 6;                    // wave id: owns cols w*16..w*16+15
  const int quad = lane >> 4, nn = lane & 15;

  // Prefetch this wave's B fragments (16 x 16B = 64 VGPRs), H and L.
  const frag8* Wt8 = (const frag8*)Wt;
  const int bbase = ((w * 16 + nn) << 5) + quad;
  frag8 bH[8], bL[8];
#pragma unroll
  for (int q = 0; q < 8; q++) {
    bH[q] = Wt8[bbase + (q << 2)];
    bL[q] = Wt8[2048 + bbase + (q << 2)];
  }

  // Stage A tile (32 rows x 256 k) coalesced; swizzle B ^= ((B>>8)&7)<<4.
  const float4* inp4 = (const float4*)inp;
  const int l5 = t & 31;
  const int rw = t >> 5;                   // row-within-group 0..7
  {
    const int q8 = l5 >> 2, qd = l5 & 3;
#pragma unroll
    for (int i = 0; i < 4; i++) {
      int row = i * 8 + rw;
      int node = n0 + row;
      float4 a0 = make_float4(0.f, 0.f, 0.f, 0.f), a1 = a0;
      if (node < NN) {
        a0 = inp4[(size_t)node * 64 + l5 * 2];
        a1 = inp4[(size_t)node * 64 + l5 * 2 + 1];
      }
      int c = ((row >> 4) << 9) | (q8 << 6) | (qd << 4) | (row & 15);
      int B = c << 4;
      B ^= ((B >> 8) & 7) << 4;
      CH ch;
      ch.u[0] = pk2(a0.x, a0.y);
      ch.u[1] = pk2(a0.z, a0.w);
      ch.u[2] = pk2(a1.x, a1.y);
      ch.u[3] = pk2(a1.z, a1.w);
      *(frag8*)(smem + B) = ch.v;
    }
  }
  __syncthreads();

  fragc accH[2], accL[2];
#pragma unroll
  for (int m = 0; m < 2; m++) {
    accH[m] = (fragc){0.f, 0.f, 0.f, 0.f};
    accL[m] = (fragc){0.f, 0.f, 0.f, 0.f};
  }

  // Pure LDS+MFMA inner loop: 16 swizzled ds_read_b128 + 32 MFMA per wave.
#pragma unroll
  for (int q = 0; q < 8; q++) {
#pragma unroll
    for (int mt = 0; mt < 2; mt++) {
      int R = (mt << 13) + (q << 10) + (lane << 4);
      R ^= ((R >> 8) & 7) << 4;
      frag8 af = *(const frag8*)(smem + R);  // A[m=nn][k=q*32+quad*8+j]
      accH[mt] = __builtin_amdgcn_mfma_f32_16x16x32_bf16(af, bH[q], accH[mt], 0, 0, 0);
      accL[mt] = __builtin_amdgcn_mfma_f32_16x16x32_bf16(af, bL[q], accL[mt], 0, 0, 0);
    }
  }
  __syncthreads();           // A-tile dead; reuse smem for cross-wave reduce

  // Epilogue: C/D mapping col=lane&15 (n), row=quad*4+reg (m89-verified).
  float* sred = (float*)smem;
  const float ahv = ah[w * 16 + nn];
  const float alv = al[w * 16 + nn];
#pragma unroll
  for (int mt = 0; mt < 2; mt++) {
#pragma unroll
    for (int r = 0; r < 4; r++) {
      int rowb = (mt << 4) + (quad << 2) + r;
      int node = n0 + rowb;
      float hH = leaky01(accH[mt][r]);
      float hL = leaky01(accL[mt][r]);
      if (node < NN) HL[(size_t)node * DOUT + w * 16 + nn] = pk2(hH, hL);
      float pH = hH * ahv, pL = hL * alv;
#pragma unroll
      for (int off = 1; off < 16; off <<= 1) {   // reduce over the 16-col slice
        pH += __shfl_xor(pH, off);
        pL += __shfl_xor(pL, off);
      }
      if (nn == 0) {
        sred[rowb * 8 + w]     = pH;
        sred[rowb * 8 + 4 + w] = pL;
      }
    }
  }
  __syncthreads();
  if (t < 32) {
    int node = n0 + t;
    if (node < NN) {
      float sH = sred[t * 8 + 0] + sred[t * 8 + 1] + sred[t * 8 + 2] + sred[t * 8 + 3];
      float sL = sred[t * 8 + 4] + sred[t * 8 + 5] + sred[t * 8 + 6] + sred[t * 8 + 7];
      ss[node] = make_float2(sH, sL);
    }
  }
}

// -------------------------------------------------------------------------
// CSR build (round-10 proven, u16 col): XCD-grouped block mapping (4 parts of
// one bucket share blockIdx%8 -> same XCD). Lists staged in LDS as u16,
// streamed out as coalesced int4.
// -------------------------------------------------------------------------
__global__ __launch_bounds__(256) void csr_kernel(
    const uint32_t* __restrict__ binned, const int* __restrict__ cursor,
    unsigned short* __restrict__ col)
{
  __shared__ __align__(16) unsigned short lst[64][CAPS];   // 12288 B
  __shared__ int cnt[64];
  const int blk = blockIdx.x;
  const int b    = ((blk >> 5) << 3) + (blk & 7);   // bucket
  const int part = (blk >> 3) & 3;                  // 64-node slice
  if (b >= BKT) return;
  const int t = threadIdx.x;
  if (t < 64) cnt[t] = 0;
  __syncthreads();
  int n = cursor[b]; if (n > BCAP) n = BCAP;
  const uint32_t* eb = binned + (size_t)b * BCAP;
  for (int i = t; i < n; i += 256) {
    uint32_t v = eb[i];
    int src = v >> 16, dst = v & 0xffff;
    int loc = src & 255;
    if ((loc >> 6) == part) {
      int pos = atomicAdd(&cnt[loc & 63], 1);
      if (pos < CAPD) lst[loc & 63][1 + pos] = (unsigned short)dst;
    }
  }
  __syncthreads();
  if (t < 64) {
    int c = cnt[t]; if (c > CAPD) c = CAPD;
    lst[t][0] = (unsigned short)c;
  }
  __syncthreads();
  // stream out 64 rows x 96 u16 = 12288 B = 768 int4, fully coalesced
  const int base_node = (b << 8) + (part << 6);
  int4* dst4 = (int4*)(col + (size_t)base_node * CAPS);
  const int4* src4 = (const int4*)&lst[0][0];
  for (int i = t; i < 64 * CAPS / 8; i += 256) {
    int node = base_node + i / (CAPS / 8);
    if (node < NN) dst4[i] = src4[i];
  }
}

// -------------------------------------------------------------------------
// agg (round-10/12 proven form, ~52 us): one wave per node; two edges per
// wave-instruction (lanes 0-31 even edge, 32-63 odd; dwordx2 covers the 256B
// HL row across a half-wave); ds_bpermute broadcasts; 4-pair batches; u16
// neighbor lists. Beyond-L2-BW bound (rounds 6/7/9 exhausted the levers).
// -------------------------------------------------------------------------
__global__ __launch_bounds__(256) void agg_kernel(
    const uint32_t* __restrict__ HL, const float2* __restrict__ ss,
    const unsigned short* __restrict__ col, float* __restrict__ out)
{
  int wave = (blockIdx.x * blockDim.x + threadIdx.x) >> 6;
  int lane = threadIdx.x & 63;
  if (wave >= NN) return;
  const int n = wave;
  const unsigned short* cl = col + (size_t)n * CAPS;
  int d = cl[0]; if (d > CAPD) d = CAPD;

  const float2 sn = ss[n];
  const uint2* HL2 = (const uint2*)HL;

  const int vodd4 = (lane & 32) >> 3;    // bperm byte-idx: +4 selects odd edge
  const int lo31  = lane & 31;           // uint2 slot within row

  float accH0 = 0.f, accH1 = 0.f, accL0 = 0.f, accL1 = 0.f;
  float rsH = 0.f, rsL = 0.f;

  for (int base = 0; base < d; base += 64) {
    int m = d - base; if (m > 64) m = 64;
    int   dst_l = 0;
    float eh_l = 0.f, el_l = 0.f;
    if (lane < m) {
      dst_l = cl[1 + base + lane];
      float2 sd = ss[dst_l];
      float xh = sn.x - sd.x;
      xh = (xh >= 0.f) ? xh : 0.2f * xh;
      eh_l = __expf(-xh);
      float xl = sn.y + sd.y;
      xl = (xl >= 0.f) ? xl : 0.2f * xl;
      el_l = __expf(-xl);
    }
    const int ehb = __float_as_int(eh_l);
    const int elb = __float_as_int(el_l);
    const int pj = (m + 1) >> 1;         // pairs in this chunk (<= 32)
    for (int jj = 0; jj < pj; jj += 4) { // 4 pairs = 8 edges per batch
      int vdd[4]; float veh[4], vel[4]; uint2 u[4];
#pragma unroll
      for (int x = 0; x < 4; x++) {
        int ib = vodd4 + ((jj + x) << 3);          // max 4+31*8=252 < 256
        vdd[x] = __builtin_amdgcn_ds_bpermute(ib, dst_l);
        veh[x] = __int_as_float(__builtin_amdgcn_ds_bpermute(ib, ehb));
        vel[x] = __int_as_float(__builtin_amdgcn_ds_bpermute(ib, elb));
      }
#pragma unroll
      for (int x = 0; x < 4; x++)
        u[x] = HL2[(((uint32_t)vdd[x]) << 5) + lo31];
#pragma unroll
      for (int x = 0; x < 4; x++) {
        accH0 += veh[x] * bfH(u[x].x);
        accL0 += vel[x] * bfL(u[x].x);
        accH1 += veh[x] * bfH(u[x].y);
        accL1 += vel[x] * bfL(u[x].y);
      }
    }
    // chunk row-sums: one butterfly over the wave (invalid lanes hold 0)
    float rh = eh_l, rl = el_l;
#pragma unroll
    for (int off = 1; off < 64; off <<= 1) {
      rh += __shfl_xor(rh, off);
      rl += __shfl_xor(rl, off);
    }
    rsH += rh; rsL += rl;
  }

  // combine even-edge (lanes 0-31) and odd-edge (lanes 32-63) partials:
  // lanes l and l+32 hold the same dim pair (2l, 2l+1).
  accH0 += __shfl_xor(accH0, 32);
  accH1 += __shfl_xor(accH1, 32);
  accL0 += __shfl_xor(accL0, 32);
  accL1 += __shfl_xor(accL1, 32);

  // lanes 0-31 write the H half (dims 2l,2l+1), lanes 32-63 the L half.
  float r  = (lane < 32) ? rsH : rsL;
  float a0 = (lane < 32) ? accH0 : accL0;
  float a1 = (lane < 32) ? accH1 : accL1;
  float inv = 1.f / (r + 1e-16f);
  float o0 = leaky01(a0 * inv);
  float o1 = leaky01(a1 * inv);
  float2* op = (float2*)(out + (size_t)n * 128 + ((lane & 32) << 1) + (lo31 << 1));
  *op = make_float2(o0, o1);
}

// -------------------------------------------------------------------------
extern "C" void kernel_launch(void* const* d_in, const int* in_sizes, int n_in,
                              void* d_out, int out_size, void* d_ws, size_t ws_size,
                              hipStream_t stream) {
  const float* inp  = (const float*)d_in[0];
  const int*   edge = (const int*)d_in[1];
  const float* Wh   = (const float*)d_in[2];
  const float* Wl   = (const float*)d_in[3];
  const float* ah   = (const float*)d_in[4];
  const float* al   = (const float*)d_in[5];
  float* out = (float*)d_out;

  char* ws = (char*)d_ws;
  uint32_t* HL     = (uint32_t*)(ws + 0);          // 12,800,000 B
  float2*   ss     = (float2*)  (ws + 12800000);   //    400,000 B
  unsigned short* col = (unsigned short*)(ws + 13200000);  // 9,600,000 B (u16)
  uint32_t* binned = (uint32_t*)(ws + 32400000);   //  8,028,160 B
  int*      cursor = (int*)     (ws + 40428160);   //        784 B
  // Wt (64 KB bf16 weights) overlays col's first bytes: read only during
  // fused_kernel; csr_kernel overwrites col strictly afterwards.
  __hip_bfloat16* Wt = (__hip_bfloat16*)(ws + 13200000);

  prep_kernel<<<128, 256, 0, stream>>>(Wh, Wl, Wt, cursor);
  fused_kernel<<<NBIN + NGEMM, 256, 0, stream>>>(inp, Wt, ah, al, edge,
                                                 cursor, binned, HL, ss);
  csr_kernel<<<800, 256, 0, stream>>>(binned, cursor, col);
  agg_kernel<<<NN / 4, 256, 0, stream>>>(HL, ss, col, out);
}